// Round 2
// baseline (160.514 us; speedup 1.0000x reference)
//
#include <hip/hip_runtime.h>
#include <math.h>

typedef unsigned int uint;
typedef unsigned short ushort;

typedef __attribute__((ext_vector_type(8))) __bf16 bf16x8;
typedef __attribute__((ext_vector_type(16))) float floatx16;
typedef __attribute__((ext_vector_type(2))) float f32x2;

#define NFEAT 327680   // 256*1280 feats (bf16)
#define NW    491520   // 128*3840 W (bf16)
// ws: fB bf16[NFEAT] | wB bf16[NW] | stats f32[16] | Aoi f32[128*256]

union U4B8 { uint4 u; bf16x8 b; };

__device__ inline ushort f2b(float f) {
  uint u = __float_as_uint(f);
  u += 0x7fffu + ((u >> 16) & 1u);   // RNE
  return (ushort)(u >> 16);
}
__device__ inline f32x2 unpk(uint u) {
  f32x2 r;
  r.x = __uint_as_float(u << 16);
  r.y = __uint_as_float(u & 0xffff0000u);
  return r;
}

#if __has_builtin(__builtin_amdgcn_cvt_pk_bf16_f32)
typedef __attribute__((ext_vector_type(2))) __bf16 bf16x2;
__device__ inline uint cvtpk(float a, float b) {
  bf16x2 r = __builtin_amdgcn_cvt_pk_bf16_f32(a, b);
  return *(uint*)&r;
}
__device__ inline uint cvtpk_abs(float a, float b) { return cvtpk(fabsf(a), fabsf(b)); }
#else
__device__ inline uint cvtpk(float a, float b) {   // round-half-up fallback
  uint au = __float_as_uint(a) + 0x8000u;
  uint bu = __float_as_uint(b) + 0x8000u;
  return __builtin_amdgcn_perm(bu, au, 0x07060302u);
}
__device__ inline uint cvtpk_abs(float a, float b) { return cvtpk(a, b) & 0x7fff7fffu; }
#endif

// async global->LDS DMA, 16B/lane; lds dest wave-uniform base (+lane*16 implicit)
__device__ inline void async16(const ushort* g, ushort* l) {
  __builtin_amdgcn_global_load_lds((const __attribute__((address_space(1))) uint*)g,
                                   (__attribute__((address_space(3))) uint*)l, 16, 0, 0);
}

// ---------------- prep: fp32 -> bf16, zero stats + Aoi ----------------
__global__ void prep_kernel(const float* __restrict__ feats,
                            const float* __restrict__ W,
                            ushort* __restrict__ fB,
                            ushort* __restrict__ wB,
                            float* __restrict__ stats,
                            float* __restrict__ Aoi) {
  int idx = blockIdx.x * 256 + threadIdx.x;   // 3200*256 = NFEAT+NW
  if (blockIdx.x == 0 && threadIdx.x < 16) stats[threadIdx.x] = 0.0f;
  if (idx < 32768) Aoi[idx] = 0.0f;
  if (idx < NFEAT) fB[idx] = f2b(feats[idx]);
  else             wB[idx - NFEAT] = f2b(W[idx - NFEAT]);
}

// ---------------- A[o,i] = sum_c Wa[o,c]*f[i,c] ----------------
// grid 128: 8 i-tiles x 4 kq x 4 ot
__global__ __launch_bounds__(256, 2) void gemma_kernel(
    const ushort* __restrict__ fB, const ushort* __restrict__ wB,
    float* __restrict__ Aoi) {
  __shared__ float red[4][1024];
  const int tid = threadIdx.x, lane = tid & 63, w = tid >> 6;
  const int i0 = (blockIdx.x >> 4) << 5;
  const int kq = (blockIdx.x >> 2) & 3;
  const int ot = blockIdx.x & 3;
  const int rr = lane & 31, half = lane >> 5;
  floatx16 a4;
  #pragma unroll
  for (int r = 0; r < 16; ++r) a4[r] = 0.0f;
  const int kbase = kq * 320 + w * 80 + half * 8;
  #pragma unroll
  for (int ks = 0; ks < 5; ++ks) {
    const int k = kbase + ks * 16;
    U4B8 bf; bf.u = *(const uint4*)(fB + (i0 + rr) * 1280 + k);
    U4B8 af; af.u = *(const uint4*)(wB + (ot * 32 + rr) * 3840 + k);
    a4 = __builtin_amdgcn_mfma_f32_32x32x16_bf16(af.b, bf.b, a4, 0, 0, 0);
  }
  #pragma unroll
  for (int r = 0; r < 16; ++r) {
    const int orow = (r & 3) + 8 * (r >> 2) + 4 * half;
    red[w][orow * 32 + rr] = a4[r];
  }
  __syncthreads();
  for (int e = tid; e < 1024; e += 256) {
    float s = red[0][e] + red[1][e] + red[2][e] + red[3][e];
    atomicAdd(&Aoi[(ot * 32 + (e >> 5)) * 256 + i0 + (e & 31)], s);
  }
}

// build diff/had B-fragments for one i from shared j-floats + fi bits
__device__ inline void build_pair(const f32x2 jv[4], const uint4 vi, U4B8& d, U4B8& h) {
  uint iu[4] = {vi.x, vi.y, vi.z, vi.w};
  uint du[4], hu[4];
  #pragma unroll
  for (int t = 0; t < 4; ++t) {
    f32x2 fv = unpk(iu[t]);
    f32x2 dd = fv - jv[t];
    f32x2 hh = fv * jv[t];
    du[t] = cvtpk_abs(dd.x, dd.y);
    hu[t] = cvtpk(hh.x, hh.y);
  }
  d.u = make_uint4(du[0], du[1], du[2], du[3]);
  h.u = make_uint4(hu[0], hu[1], hu[2], hu[3]);
}

// ---------------- main fused GEMM: diff+had, K=2560 ----------------
// R7: K-window 64 (20 iters, was 40x32) -- halve the barrier cadence.
// LDS = 2 halves x 2 tiles x 16 KB = 64 KB (2 blocks/CU in 160 KB pool).
// Per window: 8 DMAs/wave, 32 MFMAs/wave, ONE vmcnt(6)+s_barrier.
// fi/fj pipeline: st0/st1 prefetched across barrier (regs), st2/st3 issued
// at window top, consumed mid-window (L2 latency hides under st0/st1).
// vmcnt queue per window: [st01 prev(6)][st23(6)][DMA(8)][st01 next(6)];
// end-of-window vmcnt(6) retires DMAs, keeps next-st01 in flight.
// T5: setprio(1) around each ds_read+MFMA cluster.
__global__ __launch_bounds__(256, 2) void gemm_kernel(
    const ushort* __restrict__ fB, const ushort* __restrict__ wB,
    const float* __restrict__ bias, const float* __restrict__ Aoi,
    float* __restrict__ xout, float* __restrict__ stats) {
  // tile (16 KB): [row(128 o)][slot(8)*8ush], slot = octet ^ (row&7),
  // octet = term*4 + stL*2 + half.  4 tiles: half(cc&1)*2 + s.
  __shared__ __align__(16) ushort Wl[4 * 128 * 64];  // 64 KB

  const int tid = threadIdx.x;
  const int blk = blockIdx.x;          // 512 = 128 i-pairs * 4 j-blocks
  const int i0 = (blk >> 2) << 1;      // first of 2 i-rows
  const int j0 = (blk & 3) << 6;
  const int lane = tid & 63;
  const int w = tid >> 6;
  const int wo = (w >> 1) << 6;
  const int wm = (w & 1) << 5;
  const int rr = lane & 31;
  const int half = lane >> 5;
  const int rr7 = lane & 7;

  // DMA source: 8 per wave per window; DMA (w,p,tile) fills rows [(w*4+p)*8,+8)
  const ushort* gsrc[4];
  #pragma unroll
  for (int p = 0; p < 4; ++p) {
    const int seg = w * 4 + p;
    const int row = seg * 8 + (lane >> 3);
    const int g = (lane & 7) ^ (lane >> 3);
    gsrc[p] = wB + row * 3840 + 1280 + (g >> 2) * 1280 + (g & 3) * 8;
  }

  const ushort* fi0p = fB + i0 * 1280 + half * 8;
  const ushort* fi1p = fi0p + 1280;
  const ushort* fjp = fB + (j0 + wm + rr) * 1280 + half * 8;

  floatx16 acc[2][2];   // [i][ot]
  #pragma unroll
  for (int a = 0; a < 2; ++a)
    #pragma unroll
    for (int ot = 0; ot < 2; ++ot)
      #pragma unroll
      for (int r = 0; r < 16; ++r) acc[a][ot][r] = 0.0f;

  // prologue: DMA window 0 (tiles 0,1), prefetch st0/st1
  #pragma unroll
  for (int p = 0; p < 4; ++p) {
    ushort* dst = &Wl[(w * 4 + p) * 512];
    async16(gsrc[p], dst);
    async16(gsrc[p] + 32, dst + 8192);
  }
  uint4 vi0[2], vi1[2], vj[2];
  #pragma unroll
  for (int t = 0; t < 2; ++t) {
    vj[t]  = *(const uint4*)(fjp  + t * 16);
    vi0[t] = *(const uint4*)(fi0p + t * 16);
    vi1[t] = *(const uint4*)(fi1p + t * 16);
  }
  __syncthreads();   // one full drain at prologue is fine

  for (int cc = 0; cc < 20; ++cc) {
    const ushort* Wh = &Wl[(cc & 1) * 16384];
    const int cb = cc << 6;
    // group A: st2/st3 loads for CURRENT window
    uint4 vj2[2], vi02[2], vi12[2];
    #pragma unroll
    for (int t = 0; t < 2; ++t) {
      vj2[t]  = *(const uint4*)(fjp  + cb + (2 + t) * 16);
      vi02[t] = *(const uint4*)(fi0p + cb + (2 + t) * 16);
      vi12[t] = *(const uint4*)(fi1p + cb + (2 + t) * 16);
    }
    __builtin_amdgcn_sched_barrier(0);   // pin: st23 loads first
    uint4 vi0n[2], vi1n[2], vjn[2];
    if (cc < 19) {
      const int cn = (cc + 1) << 6;
      // group B: DMA next window into other half
      #pragma unroll
      for (int p = 0; p < 4; ++p) {
        ushort* dst = &Wl[((cc & 1) ^ 1) * 16384 + (w * 4 + p) * 512];
        async16(gsrc[p] + cn, dst);
        async16(gsrc[p] + cn + 32, dst + 8192);
      }
      __builtin_amdgcn_sched_barrier(0); // pin: DMAs before next-st01 loads
      // group C: next-window st0/st1 prefetch
      #pragma unroll
      for (int t = 0; t < 2; ++t) {
        vjn[t]  = *(const uint4*)(fjp  + cn + t * 16);
        vi0n[t] = *(const uint4*)(fi0p + cn + t * 16);
        vi1n[t] = *(const uint4*)(fi1p + cn + t * 16);
      }
      __builtin_amdgcn_sched_barrier(0); // pin: loads before compute
    }
    // compute: 4 sub-steps (2 tiles x 2 stL)
    #pragma unroll
    for (int s = 0; s < 2; ++s) {
      const ushort* Wc = Wh + s * 8192;
      #pragma unroll
      for (int stL = 0; stL < 2; ++stL) {
        const uint4 vjc  = (s == 0) ? vj[stL]  : vj2[stL];
        const uint4 vic0 = (s == 0) ? vi0[stL] : vi02[stL];
        const uint4 vic1 = (s == 0) ? vi1[stL] : vi12[stL];
        f32x2 jv[4];
        {
          uint ju[4] = {vjc.x, vjc.y, vjc.z, vjc.w};
          #pragma unroll
          for (int t = 0; t < 4; ++t) jv[t] = unpk(ju[t]);
        }
        U4B8 d0, h0, d1, h1;
        build_pair(jv, vic0, d0, h0);
        build_pair(jv, vic1, d1, h1);
        const int g0 = (stL << 1) + half;      // term-0 octet (0..3)
        __builtin_amdgcn_s_setprio(1);
        #pragma unroll
        for (int ot = 0; ot < 2; ++ot) {
          const int rowb = (wo + ot * 32 + rr) << 6;
          bf16x8 ad = *(const bf16x8*)(Wc + rowb + ((g0 ^ rr7) << 3));
          bf16x8 ah = *(const bf16x8*)(Wc + rowb + (((g0 + 4) ^ rr7) << 3));
          acc[0][ot] = __builtin_amdgcn_mfma_f32_32x32x16_bf16(ad, d0.b, acc[0][ot], 0, 0, 0);
          acc[1][ot] = __builtin_amdgcn_mfma_f32_32x32x16_bf16(ad, d1.b, acc[1][ot], 0, 0, 0);
          acc[0][ot] = __builtin_amdgcn_mfma_f32_32x32x16_bf16(ah, h0.b, acc[0][ot], 0, 0, 0);
          acc[1][ot] = __builtin_amdgcn_mfma_f32_32x32x16_bf16(ah, h1.b, acc[1][ot], 0, 0, 0);
        }
        __builtin_amdgcn_s_setprio(0);
      }
    }
    if (cc < 19) {
      __builtin_amdgcn_sched_barrier(0);       // keep compute (ds_reads) above
      __builtin_amdgcn_s_waitcnt(0x0F76);      // vmcnt(6): retire the 8 DMAs only
      __builtin_amdgcn_s_barrier();
      __builtin_amdgcn_sched_barrier(0);       // nothing hoists above barrier
      __asm__ volatile("" ::: "memory");       // no LDS value caching across it
      #pragma unroll
      for (int t = 0; t < 2; ++t) {
        vj[t] = vjn[t]; vi0[t] = vi0n[t]; vi1[t] = vi1n[t];
      }
    }
  }

  // epilogue: add A[o,i]+A[o,j]+b[o], store, group stats (both i-rows)
  float gs[2][2] = {{0.f, 0.f}, {0.f, 0.f}};
  float gq[2][2] = {{0.f, 0.f}, {0.f, 0.f}};
  const int jg = j0 + wm + rr;
  #pragma unroll
  for (int ii = 0; ii < 2; ++ii) {
    const int irow = i0 + ii;
    const int mglob = irow * 256 + jg;
    #pragma unroll
    for (int ot = 0; ot < 2; ++ot) {
      #pragma unroll
      for (int r = 0; r < 16; ++r) {
        const int orow = (r & 3) + 8 * (r >> 2) + 4 * half;  // D row map (m74/m101)
        const int o = wo + ot * 32 + orow;
        float x = acc[ii][ot][r] + Aoi[o * 256 + irow] + Aoi[o * 256 + jg] + bias[o];
        xout[o * 65536 + mglob] = x;
        gs[ot][r >> 3] += x;
        gq[ot][r >> 3] += x * x;
      }
    }
  }
  __syncthreads();   // full drain before LDS reuse
  float* sred = (float*)Wl;
  if (tid < 16) sred[tid] = 0.0f;
  __syncthreads();
  #pragma unroll
  for (int ot = 0; ot < 2; ++ot) {
    #pragma unroll
    for (int rg = 0; rg < 2; ++rg) {
      float s = gs[ot][rg], qv = gq[ot][rg];
      for (int off = 32; off > 0; off >>= 1) {
        s += __shfl_xor(s, off, 64);
        qv += __shfl_xor(qv, off, 64);
      }
      if (lane == 0) {
        const int g = (wo >> 4) + ot * 2 + rg;
        atomicAdd(&sred[g], s);
        atomicAdd(&sred[8 + g], qv);
      }
    }
  }
  __syncthreads();
  if (tid < 16) atomicAdd(&stats[tid], sred[tid]);
}

// ---------------- groupnorm + exact gelu, in place ----------------
__global__ void norm_kernel(float* __restrict__ xout,
                            const float* __restrict__ stats,
                            const float* __restrict__ gamma,
                            const float* __restrict__ beta) {
  const int idx = blockIdx.x * 256 + threadIdx.x;
  const int e = idx << 2;
  const int o = e >> 16;
  const int g = o >> 4;
  const float invN = 1.0f / 1048576.0f;  // 16*65536 per group
  const float mean = stats[g] * invN;
  const float var = stats[8 + g] * invN - mean * mean;
  const float inv = rsqrtf(var + 1e-5f);
  const float ga = gamma[o], be = beta[o];
  float4 v = *(float4*)(xout + e);
  float* pv = &v.x;
  #pragma unroll
  for (int t = 0; t < 4; ++t) {
    float xn = (pv[t] - mean) * inv * ga + be;
    pv[t] = 0.5f * xn * (1.0f + erff(xn * 0.70710678118654752f));
  }
  *(float4*)(xout + e) = v;
}

extern "C" void kernel_launch(void* const* d_in, const int* in_sizes, int n_in,
                              void* d_out, int out_size, void* d_ws, size_t ws_size,
                              hipStream_t stream) {
  const float* feats = (const float*)d_in[0];
  const float* W     = (const float*)d_in[1];
  const float* bias  = (const float*)d_in[2];
  const float* gamma = (const float*)d_in[3];
  const float* beta  = (const float*)d_in[4];
  float* out = (float*)d_out;

  ushort* fB = (ushort*)d_ws;
  ushort* wB = fB + NFEAT;
  float* stats = (float*)(wB + NW);
  float* Aoi = stats + 16;

  prep_kernel<<<3200, 256, 0, stream>>>(feats, W, fB, wB, stats, Aoi);
  gemma_kernel<<<128, 256, 0, stream>>>(fB, wB, Aoi);
  gemm_kernel<<<512, 256, 0, stream>>>(fB, wB, bias, Aoi, out, stats);
  norm_kernel<<<8192, 256, 0, stream>>>(out, stats, gamma, beta);
}

// Round 3
// 146.803 us; speedup vs baseline: 1.0934x; 1.0934x over previous
//
#include <hip/hip_runtime.h>
#include <math.h>

typedef unsigned int uint;
typedef unsigned short ushort;

typedef __attribute__((ext_vector_type(8))) _Float16 f16x8;
typedef __attribute__((ext_vector_type(2))) _Float16 f16x2;
typedef __attribute__((ext_vector_type(16))) float floatx16;

#define NFEAT 327680   // 256*1280 feats (f16)
#define NW    491520   // 128*3840 W (f16)
// ws: fH f16[NFEAT] | wH f16[NW] | stats f32[16] | Aoi f32[128*256]

union U4H8 { uint4 u; f16x8 h; uint w[4]; };

__device__ inline ushort f2h(float f) {
  _Float16 h = (_Float16)f;          // v_cvt_f16_f32, RNE
  union { _Float16 h; ushort s; } c; c.h = h; return c.s;
}
__device__ inline f16x2 asf16x2(uint u) {
  union { uint u; f16x2 h; } c; c.u = u; return c.h;
}
__device__ inline uint asuint(f16x2 h) {
  union { f16x2 h; uint u; } c; c.h = h; return c.u;
}

// async global->LDS DMA, 16B/lane; lds dest wave-uniform base (+lane*16 implicit)
__device__ inline void async16(const ushort* g, ushort* l) {
  __builtin_amdgcn_global_load_lds((const __attribute__((address_space(1))) uint*)g,
                                   (__attribute__((address_space(3))) uint*)l, 16, 0, 0);
}

// ---------------- prep: fp32 -> fp16, zero stats + Aoi ----------------
__global__ void prep_kernel(const float* __restrict__ feats,
                            const float* __restrict__ W,
                            ushort* __restrict__ fH,
                            ushort* __restrict__ wH,
                            float* __restrict__ stats,
                            float* __restrict__ Aoi) {
  int idx = blockIdx.x * 256 + threadIdx.x;   // 3200*256 = NFEAT+NW
  if (blockIdx.x == 0 && threadIdx.x < 16) stats[threadIdx.x] = 0.0f;
  if (idx < 32768) Aoi[idx] = 0.0f;
  if (idx < NFEAT) fH[idx] = f2h(feats[idx]);
  else             wH[idx - NFEAT] = f2h(W[idx - NFEAT]);
}

// ---------------- A[o,i] = sum_c Wa[o,c]*f[i,c] ----------------
// grid 128: 8 i-tiles x 4 kq x 4 ot
__global__ __launch_bounds__(256, 2) void gemma_kernel(
    const ushort* __restrict__ fH, const ushort* __restrict__ wH,
    float* __restrict__ Aoi) {
  __shared__ float red[4][1024];
  const int tid = threadIdx.x, lane = tid & 63, w = tid >> 6;
  const int i0 = (blockIdx.x >> 4) << 5;
  const int kq = (blockIdx.x >> 2) & 3;
  const int ot = blockIdx.x & 3;
  const int rr = lane & 31, half = lane >> 5;
  floatx16 a4;
  #pragma unroll
  for (int r = 0; r < 16; ++r) a4[r] = 0.0f;
  const int kbase = kq * 320 + w * 80 + half * 8;
  #pragma unroll
  for (int ks = 0; ks < 5; ++ks) {
    const int k = kbase + ks * 16;
    U4H8 bf; bf.u = *(const uint4*)(fH + (i0 + rr) * 1280 + k);
    U4H8 af; af.u = *(const uint4*)(wH + (ot * 32 + rr) * 3840 + k);
    a4 = __builtin_amdgcn_mfma_f32_32x32x16_f16(af.h, bf.h, a4, 0, 0, 0);
  }
  #pragma unroll
  for (int r = 0; r < 16; ++r) {
    const int orow = (r & 3) + 8 * (r >> 2) + 4 * half;
    red[w][orow * 32 + rr] = a4[r];
  }
  __syncthreads();
  for (int e = tid; e < 1024; e += 256) {
    float s = red[0][e] + red[1][e] + red[2][e] + red[3][e];
    atomicAdd(&Aoi[(ot * 32 + (e >> 5)) * 256 + i0 + (e & 31)], s);
  }
}

// build diff/had B-fragments: packed f16, no unpack/repack.
// per packed pair: v_pk_add_f16(neg) + v_and_b32 + v_pk_mul_f16 = 3 VALU
__device__ inline void build_pair(const uint4 vj, const uint4 vi, U4H8& d, U4H8& h) {
  const uint ju[4] = {vj.x, vj.y, vj.z, vj.w};
  const uint iu[4] = {vi.x, vi.y, vi.z, vi.w};
  #pragma unroll
  for (int t = 0; t < 4; ++t) {
    f16x2 a = asf16x2(iu[t]);
    f16x2 b = asf16x2(ju[t]);
    f16x2 dd = a - b;
    f16x2 hh = a * b;
    d.w[t] = asuint(dd) & 0x7fff7fffu;   // |a-b| (clear both sign bits)
    h.w[t] = asuint(hh);
  }
}

// ---------------- main fused GEMM: diff+had, K=2560 ----------------
// R8 = R1 structure (80.7us) with bf16 -> packed-f16 fragment build.
// grid 512: 2 i-rows per block, 4 waves 2x2 per... 8 waves, wave = 2i x 64o x 32j,
// 16 MFMA per chunk, XOR-swizzled 32 KB LDS dbuf, raw s_barrier + vmcnt(4).
__global__ __launch_bounds__(256, 2) void gemm_kernel(
    const ushort* __restrict__ fH, const ushort* __restrict__ wH,
    const float* __restrict__ bias, const float* __restrict__ Aoi,
    float* __restrict__ xout, float* __restrict__ stats) {
  // LDS: [buf][row(128)][slot(8)*8ush], slot = octet ^ (row&7); octet = term*4+st*2+half
  __shared__ __align__(16) ushort Wl[2 * 128 * 64];  // 32 KB

  const int tid = threadIdx.x;
  const int blk = blockIdx.x;          // 512 = 128 i-pairs * 4 j-blocks
  const int i0 = (blk >> 2) << 1;      // first of 2 i-rows
  const int j0 = (blk & 3) << 6;
  const int lane = tid & 63;
  const int w = tid >> 6;
  const int wo = (w >> 1) << 6;
  const int wm = (w & 1) << 5;
  const int rr = lane & 31;
  const int half = lane >> 5;
  const int rr7 = lane & 7;

  // DMA source: 4 per wave; DMA (w,p) fills rows [(w*4+p)*8, +8) x 8 slots
  const ushort* gsrc[4];
  #pragma unroll
  for (int p = 0; p < 4; ++p) {
    const int seg = w * 4 + p;
    const int row = seg * 8 + (lane >> 3);
    const int g = (lane & 7) ^ (lane >> 3);
    gsrc[p] = wH + row * 3840 + 1280 + (g >> 2) * 1280 + (g & 3) * 8;
  }

  const ushort* fi0p = fH + i0 * 1280 + half * 8;
  const ushort* fi1p = fi0p + 1280;
  const ushort* fjp = fH + (j0 + wm + rr) * 1280 + half * 8;

  floatx16 acc[2][2];   // [i][ot]
  #pragma unroll
  for (int a = 0; a < 2; ++a)
    #pragma unroll
    for (int ot = 0; ot < 2; ++ot)
      #pragma unroll
      for (int r = 0; r < 16; ++r) acc[a][ot][r] = 0.0f;

  // prologue: DMA chunk 0 into buf 0, prefetch fi/fj chunk 0
  #pragma unroll
  for (int p = 0; p < 4; ++p)
    async16(gsrc[p], &Wl[(w * 4 + p) * 512]);
  uint4 vi0[2], vi1[2], vj[2];
  #pragma unroll
  for (int st = 0; st < 2; ++st) {
    vj[st]  = *(const uint4*)(fjp  + st * 16);
    vi0[st] = *(const uint4*)(fi0p + st * 16);
    vi1[st] = *(const uint4*)(fi1p + st * 16);
  }
  __syncthreads();   // one full drain at prologue is fine

  for (int cc = 0; cc < 40; ++cc) {
    const ushort* Wc = &Wl[(cc & 1) * 8192];
    uint4 vi0n[2], vi1n[2], vjn[2];
    if (cc < 39) {
      const int cn = (cc + 1) << 5;
      #pragma unroll
      for (int p = 0; p < 4; ++p)
        async16(gsrc[p] + cn, &Wl[((cc & 1) ^ 1) * 8192 + (w * 4 + p) * 512]);
      __builtin_amdgcn_sched_barrier(0);   // pin: DMAs issue first
      #pragma unroll
      for (int st = 0; st < 2; ++st) {
        vjn[st]  = *(const uint4*)(fjp  + cn + st * 16);
        vi0n[st] = *(const uint4*)(fi0p + cn + st * 16);
        vi1n[st] = *(const uint4*)(fi1p + cn + st * 16);
      }
      __builtin_amdgcn_sched_barrier(0);   // pin: loads after DMAs, before compute
    }
    #pragma unroll
    for (int st = 0; st < 2; ++st) {
      U4H8 d0, h0, d1, h1;
      build_pair(vj[st], vi0[st], d0, h0);
      build_pair(vj[st], vi1[st], d1, h1);
      const int g0 = (st << 1) + half;        // term-0 octet (0..3)
      #pragma unroll
      for (int ot = 0; ot < 2; ++ot) {
        const int rowb = (wo + ot * 32 + rr) << 6;
        f16x8 ad = *(const f16x8*)(Wc + rowb + ((g0 ^ rr7) << 3));
        f16x8 ah = *(const f16x8*)(Wc + rowb + (((g0 + 4) ^ rr7) << 3));
        acc[0][ot] = __builtin_amdgcn_mfma_f32_32x32x16_f16(ad, d0.h, acc[0][ot], 0, 0, 0);
        acc[1][ot] = __builtin_amdgcn_mfma_f32_32x32x16_f16(ad, d1.h, acc[1][ot], 0, 0, 0);
        acc[0][ot] = __builtin_amdgcn_mfma_f32_32x32x16_f16(ah, h0.h, acc[0][ot], 0, 0, 0);
        acc[1][ot] = __builtin_amdgcn_mfma_f32_32x32x16_f16(ah, h1.h, acc[1][ot], 0, 0, 0);
      }
    }
    if (cc < 39) {
      __builtin_amdgcn_sched_barrier(0);       // keep compute (ds_reads) above
      __builtin_amdgcn_s_waitcnt(0x0F74);      // vmcnt(4): retire the 4 DMAs
      __builtin_amdgcn_s_barrier();
      __builtin_amdgcn_sched_barrier(0);       // nothing hoists above barrier
      __asm__ volatile("" ::: "memory");       // no LDS value caching across it
      #pragma unroll
      for (int st = 0; st < 2; ++st) {
        vj[st] = vjn[st]; vi0[st] = vi0n[st]; vi1[st] = vi1n[st];
      }
    }
  }

  // epilogue: add A[o,i]+A[o,j]+b[o], store, group stats (both i-rows)
  float gs[2][2] = {{0.f, 0.f}, {0.f, 0.f}};
  float gq[2][2] = {{0.f, 0.f}, {0.f, 0.f}};
  const int jg = j0 + wm + rr;
  #pragma unroll
  for (int ii = 0; ii < 2; ++ii) {
    const int irow = i0 + ii;
    const int mglob = irow * 256 + jg;
    #pragma unroll
    for (int ot = 0; ot < 2; ++ot) {
      #pragma unroll
      for (int r = 0; r < 16; ++r) {
        const int orow = (r & 3) + 8 * (r >> 2) + 4 * half;  // D row map (m74/m101)
        const int o = wo + ot * 32 + orow;
        float x = acc[ii][ot][r] + Aoi[o * 256 + irow] + Aoi[o * 256 + jg] + bias[o];
        xout[o * 65536 + mglob] = x;
        gs[ot][r >> 3] += x;
        gq[ot][r >> 3] += x * x;
      }
    }
  }
  __syncthreads();   // full drain before LDS reuse
  float* sred = (float*)Wl;
  if (tid < 16) sred[tid] = 0.0f;
  __syncthreads();
  #pragma unroll
  for (int ot = 0; ot < 2; ++ot) {
    #pragma unroll
    for (int rg = 0; rg < 2; ++rg) {
      float s = gs[ot][rg], qv = gq[ot][rg];
      for (int off = 32; off > 0; off >>= 1) {
        s += __shfl_xor(s, off, 64);
        qv += __shfl_xor(qv, off, 64);
      }
      if (lane == 0) {
        const int g = (wo >> 4) + ot * 2 + rg;
        atomicAdd(&sred[g], s);
        atomicAdd(&sred[8 + g], qv);
      }
    }
  }
  __syncthreads();
  if (tid < 16) atomicAdd(&stats[tid], sred[tid]);
}

// ---------------- groupnorm + exact gelu, in place ----------------
__global__ void norm_kernel(float* __restrict__ xout,
                            const float* __restrict__ stats,
                            const float* __restrict__ gamma,
                            const float* __restrict__ beta) {
  const int idx = blockIdx.x * 256 + threadIdx.x;
  const int e = idx << 2;
  const int o = e >> 16;
  const int g = o >> 4;
  const float invN = 1.0f / 1048576.0f;  // 16*65536 per group
  const float mean = stats[g] * invN;
  const float var = stats[8 + g] * invN - mean * mean;
  const float inv = rsqrtf(var + 1e-5f);
  const float ga = gamma[o], be = beta[o];
  float4 v = *(float4*)(xout + e);
  float* pv = &v.x;
  #pragma unroll
  for (int t = 0; t < 4; ++t) {
    float xn = (pv[t] - mean) * inv * ga + be;
    pv[t] = 0.5f * xn * (1.0f + erff(xn * 0.70710678118654752f));
  }
  *(float4*)(xout + e) = v;
}

extern "C" void kernel_launch(void* const* d_in, const int* in_sizes, int n_in,
                              void* d_out, int out_size, void* d_ws, size_t ws_size,
                              hipStream_t stream) {
  const float* feats = (const float*)d_in[0];
  const float* W     = (const float*)d_in[1];
  const float* bias  = (const float*)d_in[2];
  const float* gamma = (const float*)d_in[3];
  const float* beta  = (const float*)d_in[4];
  float* out = (float*)d_out;

  ushort* fH = (ushort*)d_ws;
  ushort* wH = fH + NFEAT;
  float* stats = (float*)(wH + NW);
  float* Aoi = stats + 16;

  prep_kernel<<<3200, 256, 0, stream>>>(feats, W, fH, wH, stats, Aoi);
  gemma_kernel<<<128, 256, 0, stream>>>(fH, wH, Aoi);
  gemm_kernel<<<512, 256, 0, stream>>>(fH, wH, bias, Aoi, out, stats);
  norm_kernel<<<8192, 256, 0, stream>>>(out, stats, gamma, beta);
}